// Round 17
// baseline (274.698 us; speedup 1.0000x reference)
//
#include <hip/hip_runtime.h>
#include <hip/hip_bf16.h>
#include <cstdint>
#include <cstddef>

#define BT    16384   // B*T
#define DIN   4096
#define DOUT  4096
#define RR    64
#define TSEQ  2048
#define NADP  8
#define NCH   16      // K-chunks in split-K GEMM-1
#define KCH   (DIN / NCH)   // 256

typedef float  f32x4  __attribute__((ext_vector_type(4)));
typedef __bf16 bf16x8 __attribute__((ext_vector_type(8)));

static __device__ __forceinline__ unsigned short bf16_bits(float f) {
    return __builtin_bit_cast(unsigned short, (__bf16)f);
}

// inter2 swizzled layout: [mblk(1024)][rb(8)][mrow(16)][j(8)]
static __device__ __forceinline__ size_t i2_idx(int mblk, int rb, int mrow, int j) {
    return ((((size_t)mblk * 8 + rb) * 16 + mrow) * 8 + j);
}

static __device__ __forceinline__ bf16x8 cvt8(float4 a, float4 b) {
    bf16x8 v;
    v[0] = (__bf16)a.x; v[1] = (__bf16)a.y; v[2] = (__bf16)a.z; v[3] = (__bf16)a.w;
    v[4] = (__bf16)b.x; v[5] = (__bf16)b.y; v[6] = (__bf16)b.z; v[7] = (__bf16)b.w;
    return v;
}

// ---------------------------------------------------------------------------
// k_prep_a: At2[a][kq][r][j] = bf16(A[a][kq*8+j][r]).  (R8+ verbatim)
// ---------------------------------------------------------------------------
__global__ __launch_bounds__(256) void k_prep_a(
    const float* __restrict__ A, __bf16* __restrict__ At2)
{
    const int gtid = blockIdx.x * 256 + threadIdx.x;
    const int r  = gtid & 63;
    const int kb = (gtid >> 6) & (DIN / 8 - 1);
    const int a  = gtid >> 15;
    const float* __restrict__ src = A + (size_t)a * DIN * RR + (size_t)kb * 8 * RR + r;
    unsigned int u[4];
    #pragma unroll
    for (int p = 0; p < 4; ++p) {
        unsigned int lo = bf16_bits(src[(2 * p + 0) * RR]);
        unsigned int hi = bf16_bits(src[(2 * p + 1) * RR]);
        u[p] = lo | (hi << 16);
    }
    *(uint4*)&At2[(size_t)gtid * 8] = make_uint4(u[0], u[1], u[2], u[3]);
}

// ---------------------------------------------------------------------------
// k_prep_b: Bp[a][rb][o][j] = bf16(B[a][rb*8+j][o]).  (R8+ verbatim)
// ---------------------------------------------------------------------------
__global__ __launch_bounds__(256) void k_prep_b(
    const float* __restrict__ Bw, __bf16* __restrict__ Bp)
{
    const int gtid = blockIdx.x * 256 + threadIdx.x;
    const int o  = gtid & (DOUT - 1);
    const int rb = (gtid >> 12) & 7;
    const int a  = gtid >> 15;
    const float* __restrict__ src = Bw + (size_t)a * RR * DOUT + (size_t)rb * 8 * DOUT + o;
    unsigned int u[4];
    #pragma unroll
    for (int p = 0; p < 4; ++p) {
        unsigned int lo = bf16_bits(src[(2 * p + 0) * DOUT]);
        unsigned int hi = bf16_bits(src[(2 * p + 1) * DOUT]);
        u[p] = lo | (hi << 16);
    }
    *(uint4*)&Bp[(size_t)gtid * 8] = make_uint4(u[0], u[1], u[2], u[3]);
}

// ---------------------------------------------------------------------------
// k_xa_split: parts[kc] <- bf16( x[:, kc*256:+256] @ A[a][kc slice] ).
// R16 indexing verbatim; NEW: __launch_bounds__(256,4) (VGPR cap 128, 4
// waves/SIMD) + ALL 24 loads hoisted into static-indexed locals BEFORE the
// MFMA chain -> compiler must batch-issue them (in-flight ~24KB/wave).
// ---------------------------------------------------------------------------
__global__ __launch_bounds__(256, 4) void k_xa_split(
    const float* __restrict__ x, const int* __restrict__ idx,
    const __bf16* __restrict__ At2, __bf16* __restrict__ parts)
{
    const int mb   = blockIdx.x;           // 16-row m-block, 0..1023
    const int kc   = blockIdx.y;           // K-chunk, 0..15
    const int m0   = mb * 16;
    const int a    = idx[m0 / TSEQ];
    const int rw   = threadIdx.x >> 6, lane = threadIdx.x & 63;
    const int mr   = lane & 15, kg = lane >> 4;
    const int rcol = rw * 16 + mr;

    const float*  __restrict__ xrow = x + (size_t)(m0 + mr) * DIN + kc * KCH + kg * 8;
    const __bf16* __restrict__ Aw   = At2 + (size_t)a * RR * DIN;
    const int kqb = kc * (KCH / 8);        // base k-octet index for this chunk

    // ---- issue ALL loads first (static indices -> registers, rule #20) ----
    float4 xv0[8], xv1[8];
    bf16x8 av[8];
    #pragma unroll
    for (int step = 0; step < 8; ++step) {
        xv0[step] = *(const float4*)(xrow + step * 32);
        xv1[step] = *(const float4*)(xrow + step * 32 + 4);
    }
    #pragma unroll
    for (int step = 0; step < 8; ++step)
        av[step] = *(const bf16x8*)&Aw[((size_t)(kqb + step * 4 + kg) * 64 + rcol) * 8];

    // ---- then the MFMA chain ----
    f32x4 acc = {0.f, 0.f, 0.f, 0.f};
    #pragma unroll
    for (int step = 0; step < 8; ++step)
        acc = __builtin_amdgcn_mfma_f32_16x16x32_bf16(cvt8(xv0[step], xv1[step]),
                                                      av[step], acc, 0, 0, 0);

    // store to partial kc (i2 layout, scalar bf16 stores = R11-proven)
    __bf16* __restrict__ part = parts + (size_t)kc * (BT / 16) * 1024;
    const int rb = rw * 2 + (mr >> 3), j = mr & 7;
    #pragma unroll
    for (int q = 0; q < 4; ++q)
        part[i2_idx(mb, rb, kg * 4 + q, j)] = (__bf16)acc[q];
}

// ---------------------------------------------------------------------------
// k_reduce: inter2 = bf16( sum_kc parts[kc] ).  NEW: launch_bounds(256,4)
// so the 16 independent 16B loads batch-issue instead of serializing.
// ---------------------------------------------------------------------------
__global__ __launch_bounds__(256, 4) void k_reduce(
    const __bf16* __restrict__ parts, __bf16* __restrict__ inter2)
{
    const int t = blockIdx.x * 256 + threadIdx.x;      // 0..131071
    const size_t off = (size_t)t * 8;                  // i2 flat offset
    bf16x8 v[NCH];
    #pragma unroll
    for (int c = 0; c < NCH; ++c)
        v[c] = *(const bf16x8*)&parts[(size_t)c * (BT / 16) * 1024 + off];
    float s[8] = {};
    #pragma unroll
    for (int c = 0; c < NCH; ++c)
        #pragma unroll
        for (int e = 0; e < 8; ++e) s[e] += (float)v[c][e];
    unsigned int u[4];
    #pragma unroll
    for (int p = 0; p < 4; ++p) {
        unsigned int lo = bf16_bits(s[2 * p + 0]);
        unsigned int hi = bf16_bits(s[2 * p + 1]);
        u[p] = lo | (hi << 16);
    }
    *(uint4*)&inter2[off] = make_uint4(u[0], u[1], u[2], u[3]);
}

// ---------------------------------------------------------------------------
// k_by: out = base + s * (inter @ B).  (R8/R11/R13 verbatim, ~6.5 TB/s)
// ---------------------------------------------------------------------------
__global__ __launch_bounds__(256) void k_by(
    const __bf16* __restrict__ inter2, const float* __restrict__ base,
    const int* __restrict__ idx, const __bf16* __restrict__ Bp,
    const float* __restrict__ scal, float* __restrict__ out)
{
    const int o0 = blockIdx.x * 64;
    const int m0 = blockIdx.y * 64;
    const int a  = idx[m0 / TSEQ];
    const float s = scal[a];
    const __bf16* __restrict__ Ba = Bp + (size_t)a * RR * DOUT;
    const int lane = threadIdx.x & 63;
    const int w    = threadIdx.x >> 6;
    const int mr   = lane & 15, kg = lane >> 4;
    const int oc   = o0 + w * 16 + mr;

    f32x4 z = {0.f, 0.f, 0.f, 0.f};
    f32x4 acc[4] = {z, z, z, z};

    #pragma unroll
    for (int ksub = 0; ksub < 2; ++ksub) {
        const int rb = ksub * 4 + kg;
        bf16x8 bfA = *(const bf16x8*)&Ba[((size_t)rb * DOUT + oc) * 8];
        #pragma unroll
        for (int mt = 0; mt < 4; ++mt) {
            bf16x8 afB = *(const bf16x8*)&inter2[i2_idx(m0 / 16 + mt, rb, mr, 0)];
            acc[mt] = __builtin_amdgcn_mfma_f32_16x16x32_bf16(bfA, afB, acc[mt], 0, 0, 0);
        }
    }

    #pragma unroll
    for (int mt = 0; mt < 4; ++mt) {
        size_t off = (size_t)(m0 + mt * 16 + mr) * DOUT + o0 + w * 16 + kg * 4;
        float4 bv = *(const float4*)&base[off];
        float4 o;
        o.x = bv.x + s * acc[mt][0];
        o.y = bv.y + s * acc[mt][1];
        o.z = bv.z + s * acc[mt][2];
        o.w = bv.w + s * acc[mt][3];
        *(float4*)&out[off] = o;
    }
}

// ---------------------------------------------------------------------------
// Tier-2 k_xa (R11 register-pipeline, proven, ~117 us) for 10 MB ws.
// ---------------------------------------------------------------------------
__global__ __launch_bounds__(256, 1) void k_xa(
    const float* __restrict__ x, const int* __restrict__ idx,
    const __bf16* __restrict__ At2, __bf16* __restrict__ inter2)
{
    const int m0   = blockIdx.x * 64;
    const int a    = idx[m0 / TSEQ];
    const int w    = threadIdx.x >> 6, lane = threadIdx.x & 63;
    const int mr   = lane & 15, kg = lane >> 4;
    const float*  __restrict__ xrow = x + (size_t)(m0 + w * 16 + mr) * DIN + kg * 8;
    const __bf16* __restrict__ Aw = At2 + (size_t)a * RR * DIN + (size_t)(kg * 64 + mr) * 8;

    f32x4 z = {0.f, 0.f, 0.f, 0.f};
    f32x4 acc[4] = {z, z, z, z};
    float4 sx0[4], sx1[4];
    bf16x8 sa[4][4];

    #pragma unroll
    for (int s = 0; s < 4; ++s) {
        sx0[s] = *(const float4*)(xrow + s * 32);
        sx1[s] = *(const float4*)(xrow + s * 32 + 4);
        #pragma unroll
        for (int n = 0; n < 4; ++n)
            sa[s][n] = *(const bf16x8*)(Aw + ((size_t)s * 256 + n * 16) * 8);
    }

    #pragma unroll 4
    for (int ks = 0; ks < 124; ++ks) {
        const int s = ks & 3;
        float4 u0 = sx0[s], u1 = sx1[s];
        bf16x8 a0 = sa[s][0], a1 = sa[s][1], a2 = sa[s][2], a3 = sa[s][3];
        sx0[s] = *(const float4*)(xrow + (ks + 4) * 32);
        sx1[s] = *(const float4*)(xrow + (ks + 4) * 32 + 4);
        #pragma unroll
        for (int n = 0; n < 4; ++n)
            sa[s][n] = *(const bf16x8*)(Aw + ((size_t)(ks + 4) * 256 + n * 16) * 8);
        bf16x8 af = cvt8(u0, u1);
        acc[0] = __builtin_amdgcn_mfma_f32_16x16x32_bf16(af, a0, acc[0], 0, 0, 0);
        acc[1] = __builtin_amdgcn_mfma_f32_16x16x32_bf16(af, a1, acc[1], 0, 0, 0);
        acc[2] = __builtin_amdgcn_mfma_f32_16x16x32_bf16(af, a2, acc[2], 0, 0, 0);
        acc[3] = __builtin_amdgcn_mfma_f32_16x16x32_bf16(af, a3, acc[3], 0, 0, 0);
    }
    #pragma unroll
    for (int ks = 124; ks < 128; ++ks) {
        const int s = ks & 3;
        bf16x8 af = cvt8(sx0[s], sx1[s]);
        #pragma unroll
        for (int n = 0; n < 4; ++n)
            acc[n] = __builtin_amdgcn_mfma_f32_16x16x32_bf16(af, sa[s][n], acc[n], 0, 0, 0);
    }

    const int mblk = blockIdx.x * 4 + w;
    #pragma unroll
    for (int n = 0; n < 4; ++n) {
        const int rb = n * 2 + (mr >> 3), j = mr & 7;
        #pragma unroll
        for (int q = 0; q < 4; ++q)
            inter2[i2_idx(mblk, rb, kg * 4 + q, j)] = (__bf16)acc[n][q];
    }
}

// ---------------------------------------------------------------------------
// Fallback kernels (R6 verbatim, 2 MB ws).
// ---------------------------------------------------------------------------
__global__ __launch_bounds__(256) void k_xa_fb(
    const float* __restrict__ x, const int* __restrict__ idx,
    const float* __restrict__ A, __bf16* __restrict__ inter)
{
    const int m0   = blockIdx.x * 32;
    const int a    = idx[m0 / TSEQ];
    const float* __restrict__ Aa = A + (size_t)a * DIN * RR;
    const int lane = threadIdx.x & 63;
    const int rw   = threadIdx.x >> 6;
    const int mr   = lane & 15, kg = lane >> 4;
    const int rcol = rw * 16 + mr;
    const float* __restrict__ xrow0 = x + (size_t)(m0 + mr) * DIN;
    const float* __restrict__ xrow1 = x + (size_t)(m0 + 16 + mr) * DIN;

    f32x4 acc0 = {0.f, 0.f, 0.f, 0.f};
    f32x4 acc1 = {0.f, 0.f, 0.f, 0.f};

    for (int k0 = 0; k0 < DIN; k0 += 64) {
        #pragma unroll
        for (int ksub = 0; ksub < 2; ++ksub) {
            const int koff = k0 + ksub * 32 + kg * 8;
            float4 u0 = *(const float4*)&xrow0[koff];
            float4 u1 = *(const float4*)&xrow0[koff + 4];
            float4 v0 = *(const float4*)&xrow1[koff];
            float4 v1 = *(const float4*)&xrow1[koff + 4];
            bf16x8 af0 = cvt8(u0, u1);
            bf16x8 af1 = cvt8(v0, v1);
            const float* ap = &Aa[(size_t)koff * RR + rcol];
            bf16x8 bf;
            bf[0] = (__bf16)ap[0 * RR]; bf[1] = (__bf16)ap[1 * RR];
            bf[2] = (__bf16)ap[2 * RR]; bf[3] = (__bf16)ap[3 * RR];
            bf[4] = (__bf16)ap[4 * RR]; bf[5] = (__bf16)ap[5 * RR];
            bf[6] = (__bf16)ap[6 * RR]; bf[7] = (__bf16)ap[7 * RR];
            acc0 = __builtin_amdgcn_mfma_f32_16x16x32_bf16(af0, bf, acc0, 0, 0, 0);
            acc1 = __builtin_amdgcn_mfma_f32_16x16x32_bf16(af1, bf, acc1, 0, 0, 0);
        }
    }
    #pragma unroll
    for (int q = 0; q < 4; ++q) {
        inter[(size_t)(m0 + kg * 4 + q) * RR + rcol]      = (__bf16)acc0[q];
        inter[(size_t)(m0 + 16 + kg * 4 + q) * RR + rcol] = (__bf16)acc1[q];
    }
}

__global__ __launch_bounds__(256) void k_by_fb(
    const __bf16* __restrict__ inter, const float* __restrict__ base,
    const int* __restrict__ idx, const float* __restrict__ Bw,
    const float* __restrict__ scal, float* __restrict__ out)
{
    const int o0 = blockIdx.x * 64;
    const int m0 = blockIdx.y * 64;
    const int a  = idx[m0 / TSEQ];
    const float s = scal[a];
    const float* __restrict__ Ba = Bw + (size_t)a * RR * DOUT;
    const int lane = threadIdx.x & 63;
    const int w    = threadIdx.x >> 6;
    const int mr   = lane & 15, kg = lane >> 4;
    const int oc   = o0 + w * 16 + mr;

    f32x4 z = {0.f, 0.f, 0.f, 0.f};
    f32x4 acc[4] = {z, z, z, z};

    #pragma unroll
    for (int ksub = 0; ksub < 2; ++ksub) {
        const int kb = ksub * 32 + kg * 8;
        const float* bp = &Ba[(size_t)kb * DOUT + oc];
        bf16x8 bf;
        bf[0] = (__bf16)bp[0 * DOUT]; bf[1] = (__bf16)bp[1 * DOUT];
        bf[2] = (__bf16)bp[2 * DOUT]; bf[3] = (__bf16)bp[3 * DOUT];
        bf[4] = (__bf16)bp[4 * DOUT]; bf[5] = (__bf16)bp[5 * DOUT];
        bf[6] = (__bf16)bp[6 * DOUT]; bf[7] = (__bf16)bp[7 * DOUT];
        #pragma unroll
        for (int mt = 0; mt < 4; ++mt) {
            bf16x8 af = *(const bf16x8*)&inter[(size_t)(m0 + mt * 16 + mr) * RR + kb];
            acc[mt] = __builtin_amdgcn_mfma_f32_16x16x32_bf16(af, bf, acc[mt], 0, 0, 0);
        }
    }
    #pragma unroll
    for (int mt = 0; mt < 4; ++mt) {
        #pragma unroll
        for (int q = 0; q < 4; ++q) {
            size_t off = (size_t)(m0 + mt * 16 + kg * 4 + q) * DOUT + oc;
            out[off] = base[off] + s * acc[mt][q];
        }
    }
}

// ---------------------------------------------------------------------------
extern "C" void kernel_launch(void* const* d_in, const int* in_sizes, int n_in,
                              void* d_out, int out_size, void* d_ws, size_t ws_size,
                              hipStream_t stream)
{
    const float* x    = (const float*)d_in[0];
    const float* base = (const float*)d_in[1];
    const int*   idx  = (const int*)  d_in[2];
    const float* A    = (const float*)d_in[3];
    const float* Bw   = (const float*)d_in[4];
    const float* scal = (const float*)d_in[5];
    float* out = (float*)d_out;

    const size_t INTER_B = (size_t)BT * RR * 2;              // 2 MB
    const size_t AT_B    = (size_t)NADP * RR * DIN * 2;      // 4 MB
    const size_t BT_B    = (size_t)NADP * DOUT * RR * 2;     // 4 MB
    const size_t PART_B  = (size_t)NCH * INTER_B;            // 32 MB

    if (ws_size >= INTER_B + AT_B + BT_B + PART_B) {         // 42 MB: split-K
        __bf16* inter2 = (__bf16*)d_ws;
        __bf16* At2    = (__bf16*)((char*)d_ws + INTER_B);
        __bf16* Bp     = (__bf16*)((char*)d_ws + INTER_B + AT_B);
        __bf16* parts  = (__bf16*)((char*)d_ws + INTER_B + AT_B + BT_B);
        k_prep_a<<<dim3(1024), 256, 0, stream>>>(A, At2);
        k_prep_b<<<dim3(1024), 256, 0, stream>>>(Bw, Bp);
        k_xa_split<<<dim3(BT / 16, NCH), 256, 0, stream>>>(x, idx, At2, parts);
        k_reduce<<<dim3(512),            256, 0, stream>>>(parts, inter2);
        k_by<<<dim3(DOUT / 64, BT / 64), 256, 0, stream>>>(inter2, base, idx, Bp, scal, out);
    } else if (ws_size >= INTER_B + AT_B + BT_B) {           // 10 MB: R11 path
        __bf16* inter2 = (__bf16*)d_ws;
        __bf16* At2    = (__bf16*)((char*)d_ws + INTER_B);
        __bf16* Bp     = (__bf16*)((char*)d_ws + INTER_B + AT_B);
        k_prep_a<<<dim3(1024), 256, 0, stream>>>(A, At2);
        k_prep_b<<<dim3(1024), 256, 0, stream>>>(Bw, Bp);
        k_xa<<<dim3(BT / 64),            256, 0, stream>>>(x, idx, At2, inter2);
        k_by<<<dim3(DOUT / 64, BT / 64), 256, 0, stream>>>(inter2, base, idx, Bp, scal, out);
    } else {                                                 // 2 MB fallback
        __bf16* inter = (__bf16*)d_ws;
        k_xa_fb<<<dim3(BT / 32),            256, 0, stream>>>(x, idx, A, inter);
        k_by_fb<<<dim3(DOUT / 64, BT / 64), 256, 0, stream>>>(inter, base, idx, Bw, scal, out);
    }
}

// Round 18
// 213.124 us; speedup vs baseline: 1.2889x; 1.2889x over previous
//
#include <hip/hip_runtime.h>
#include <hip/hip_bf16.h>
#include <cstdint>
#include <cstddef>

#define BT    16384   // B*T
#define DIN   4096
#define DOUT  4096
#define RR    64
#define TSEQ  2048
#define NADP  8
#define NCH   16      // K-chunks in split-K GEMM-1
#define KCH   (DIN / NCH)   // 256

typedef float  f32x4  __attribute__((ext_vector_type(4)));
typedef __bf16 bf16x8 __attribute__((ext_vector_type(8)));

static __device__ __forceinline__ unsigned short bf16_bits(float f) {
    return __builtin_bit_cast(unsigned short, (__bf16)f);
}

// inter2 swizzled layout: [mblk(1024)][rb(8)][mrow(16)][j(8)]
static __device__ __forceinline__ size_t i2_idx(int mblk, int rb, int mrow, int j) {
    return ((((size_t)mblk * 8 + rb) * 16 + mrow) * 8 + j);
}

static __device__ __forceinline__ bf16x8 cvt8(float4 a, float4 b) {
    bf16x8 v;
    v[0] = (__bf16)a.x; v[1] = (__bf16)a.y; v[2] = (__bf16)a.z; v[3] = (__bf16)a.w;
    v[4] = (__bf16)b.x; v[5] = (__bf16)b.y; v[6] = (__bf16)b.z; v[7] = (__bf16)b.w;
    return v;
}

// ---------------------------------------------------------------------------
// k_prep_a: At2[a][kq][r][j] = bf16(A[a][kq*8+j][r]).  (R8+ verbatim)
// ---------------------------------------------------------------------------
__global__ __launch_bounds__(256) void k_prep_a(
    const float* __restrict__ A, __bf16* __restrict__ At2)
{
    const int gtid = blockIdx.x * 256 + threadIdx.x;
    const int r  = gtid & 63;
    const int kb = (gtid >> 6) & (DIN / 8 - 1);
    const int a  = gtid >> 15;
    const float* __restrict__ src = A + (size_t)a * DIN * RR + (size_t)kb * 8 * RR + r;
    unsigned int u[4];
    #pragma unroll
    for (int p = 0; p < 4; ++p) {
        unsigned int lo = bf16_bits(src[(2 * p + 0) * RR]);
        unsigned int hi = bf16_bits(src[(2 * p + 1) * RR]);
        u[p] = lo | (hi << 16);
    }
    *(uint4*)&At2[(size_t)gtid * 8] = make_uint4(u[0], u[1], u[2], u[3]);
}

// ---------------------------------------------------------------------------
// k_prep_b: Bp[a][rb][o][j] = bf16(B[a][rb*8+j][o]).  (R8+ verbatim)
// ---------------------------------------------------------------------------
__global__ __launch_bounds__(256) void k_prep_b(
    const float* __restrict__ Bw, __bf16* __restrict__ Bp)
{
    const int gtid = blockIdx.x * 256 + threadIdx.x;
    const int o  = gtid & (DOUT - 1);
    const int rb = (gtid >> 12) & 7;
    const int a  = gtid >> 15;
    const float* __restrict__ src = Bw + (size_t)a * RR * DOUT + (size_t)rb * 8 * DOUT + o;
    unsigned int u[4];
    #pragma unroll
    for (int p = 0; p < 4; ++p) {
        unsigned int lo = bf16_bits(src[(2 * p + 0) * DOUT]);
        unsigned int hi = bf16_bits(src[(2 * p + 1) * DOUT]);
        u[p] = lo | (hi << 16);
    }
    *(uint4*)&Bp[(size_t)gtid * 8] = make_uint4(u[0], u[1], u[2], u[3]);
}

// ---------------------------------------------------------------------------
// k_xa_deep: parts[kc] <- bf16( x[:, kc*256:+256] @ A[a][kc slice] ).
// VMEM-instruction-minimal tiling: wave = 64 m-rows x 64 r (16 MFMA chains);
// per K-32 step: 8 x-loads + 4 A-loads (A SHARED across the 4 m-frags) for
// 16 MFMAs. Total VMEM = 387k instrs (vs R16's 1.57M) -> ~2.4x faster under
// the measured ~50cy/VMEM-instr throughput limit. x read exactly once.
// grid (64 m-superblocks, 16 kc) x 4 waves = 4096 waves (4/SIMD at cap 3).
// Fragment & store conventions = R11/R16 verbatim.
// ---------------------------------------------------------------------------
__global__ __launch_bounds__(256, 3) void k_xa_deep(
    const float* __restrict__ x, const int* __restrict__ idx,
    const __bf16* __restrict__ At2, __bf16* __restrict__ parts)
{
    const int bx = blockIdx.x;             // m superblock (256 rows), 0..63
    const int kc = blockIdx.y;             // K-chunk, 0..15
    const int m0 = bx * 256;
    const int a  = idx[m0 / TSEQ];
    const int w  = threadIdx.x >> 6, lane = threadIdx.x & 63;
    const int mr = lane & 15, kg = lane >> 4;
    const int mw = m0 + w * 64;            // wave's 64 rows

    const __bf16* __restrict__ Aw = At2 + (size_t)a * RR * DIN;
    const int kqb = kc * 32;               // base k-octet of this chunk

    const float* __restrict__ xr0 = x + (size_t)(mw +  0 + mr) * DIN + kc * KCH + kg * 8;
    const float* __restrict__ xr1 = x + (size_t)(mw + 16 + mr) * DIN + kc * KCH + kg * 8;
    const float* __restrict__ xr2 = x + (size_t)(mw + 32 + mr) * DIN + kc * KCH + kg * 8;
    const float* __restrict__ xr3 = x + (size_t)(mw + 48 + mr) * DIN + kc * KCH + kg * 8;

    f32x4 z = {0.f, 0.f, 0.f, 0.f};
    f32x4 acc[4][4] = {{z, z, z, z}, {z, z, z, z}, {z, z, z, z}, {z, z, z, z}};

    #pragma unroll
    for (int step = 0; step < 8; ++step) {
        // 8 x-loads (4 m-frags x 2) + 4 A-loads (r-frags, shared over m)
        float4 u00 = *(const float4*)(xr0 + step * 32);
        float4 u01 = *(const float4*)(xr0 + step * 32 + 4);
        float4 u10 = *(const float4*)(xr1 + step * 32);
        float4 u11 = *(const float4*)(xr1 + step * 32 + 4);
        float4 u20 = *(const float4*)(xr2 + step * 32);
        float4 u21 = *(const float4*)(xr2 + step * 32 + 4);
        float4 u30 = *(const float4*)(xr3 + step * 32);
        float4 u31 = *(const float4*)(xr3 + step * 32 + 4);
        const size_t kqo = (size_t)(kqb + step * 4 + kg) * 64;
        bf16x8 av0 = *(const bf16x8*)&Aw[(kqo +  0 + mr) * 8];
        bf16x8 av1 = *(const bf16x8*)&Aw[(kqo + 16 + mr) * 8];
        bf16x8 av2 = *(const bf16x8*)&Aw[(kqo + 32 + mr) * 8];
        bf16x8 av3 = *(const bf16x8*)&Aw[(kqo + 48 + mr) * 8];

        bf16x8 f0 = cvt8(u00, u01);
        bf16x8 f1 = cvt8(u10, u11);
        bf16x8 f2 = cvt8(u20, u21);
        bf16x8 f3 = cvt8(u30, u31);

        acc[0][0] = __builtin_amdgcn_mfma_f32_16x16x32_bf16(f0, av0, acc[0][0], 0, 0, 0);
        acc[0][1] = __builtin_amdgcn_mfma_f32_16x16x32_bf16(f0, av1, acc[0][1], 0, 0, 0);
        acc[0][2] = __builtin_amdgcn_mfma_f32_16x16x32_bf16(f0, av2, acc[0][2], 0, 0, 0);
        acc[0][3] = __builtin_amdgcn_mfma_f32_16x16x32_bf16(f0, av3, acc[0][3], 0, 0, 0);
        acc[1][0] = __builtin_amdgcn_mfma_f32_16x16x32_bf16(f1, av0, acc[1][0], 0, 0, 0);
        acc[1][1] = __builtin_amdgcn_mfma_f32_16x16x32_bf16(f1, av1, acc[1][1], 0, 0, 0);
        acc[1][2] = __builtin_amdgcn_mfma_f32_16x16x32_bf16(f1, av2, acc[1][2], 0, 0, 0);
        acc[1][3] = __builtin_amdgcn_mfma_f32_16x16x32_bf16(f1, av3, acc[1][3], 0, 0, 0);
        acc[2][0] = __builtin_amdgcn_mfma_f32_16x16x32_bf16(f2, av0, acc[2][0], 0, 0, 0);
        acc[2][1] = __builtin_amdgcn_mfma_f32_16x16x32_bf16(f2, av1, acc[2][1], 0, 0, 0);
        acc[2][2] = __builtin_amdgcn_mfma_f32_16x16x32_bf16(f2, av2, acc[2][2], 0, 0, 0);
        acc[2][3] = __builtin_amdgcn_mfma_f32_16x16x32_bf16(f2, av3, acc[2][3], 0, 0, 0);
        acc[3][0] = __builtin_amdgcn_mfma_f32_16x16x32_bf16(f3, av0, acc[3][0], 0, 0, 0);
        acc[3][1] = __builtin_amdgcn_mfma_f32_16x16x32_bf16(f3, av1, acc[3][1], 0, 0, 0);
        acc[3][2] = __builtin_amdgcn_mfma_f32_16x16x32_bf16(f3, av2, acc[3][2], 0, 0, 0);
        acc[3][3] = __builtin_amdgcn_mfma_f32_16x16x32_bf16(f3, av3, acc[3][3], 0, 0, 0);
    }

    // store (R11 convention per m-frag): mblk = global_row/16
    __bf16* __restrict__ part = parts + (size_t)kc * (BT / 16) * 1024;
    const int jj = mr & 7;
    #pragma unroll
    for (int mf = 0; mf < 4; ++mf) {
        const int mblk = bx * 16 + w * 4 + mf;
        #pragma unroll
        for (int n = 0; n < 4; ++n) {
            const int rb = n * 2 + (mr >> 3);
            #pragma unroll
            for (int q = 0; q < 4; ++q)
                part[i2_idx(mblk, rb, kg * 4 + q, jj)] = (__bf16)acc[mf][n][q];
        }
    }
}

// ---------------------------------------------------------------------------
// k_reduce: inter2 = bf16( sum_kc parts[kc] ).  (R17 verbatim)
// ---------------------------------------------------------------------------
__global__ __launch_bounds__(256, 4) void k_reduce(
    const __bf16* __restrict__ parts, __bf16* __restrict__ inter2)
{
    const int t = blockIdx.x * 256 + threadIdx.x;      // 0..131071
    const size_t off = (size_t)t * 8;
    bf16x8 v[NCH];
    #pragma unroll
    for (int c = 0; c < NCH; ++c)
        v[c] = *(const bf16x8*)&parts[(size_t)c * (BT / 16) * 1024 + off];
    float s[8] = {};
    #pragma unroll
    for (int c = 0; c < NCH; ++c)
        #pragma unroll
        for (int e = 0; e < 8; ++e) s[e] += (float)v[c][e];
    unsigned int u[4];
    #pragma unroll
    for (int p = 0; p < 4; ++p) {
        unsigned int lo = bf16_bits(s[2 * p + 0]);
        unsigned int hi = bf16_bits(s[2 * p + 1]);
        u[p] = lo | (hi << 16);
    }
    *(uint4*)&inter2[off] = make_uint4(u[0], u[1], u[2], u[3]);
}

// ---------------------------------------------------------------------------
// k_by: out = base + s * (inter @ B).  (R8/R11/R13 verbatim, ~6.5 TB/s)
// ---------------------------------------------------------------------------
__global__ __launch_bounds__(256) void k_by(
    const __bf16* __restrict__ inter2, const float* __restrict__ base,
    const int* __restrict__ idx, const __bf16* __restrict__ Bp,
    const float* __restrict__ scal, float* __restrict__ out)
{
    const int o0 = blockIdx.x * 64;
    const int m0 = blockIdx.y * 64;
    const int a  = idx[m0 / TSEQ];
    const float s = scal[a];
    const __bf16* __restrict__ Ba = Bp + (size_t)a * RR * DOUT;
    const int lane = threadIdx.x & 63;
    const int w    = threadIdx.x >> 6;
    const int mr   = lane & 15, kg = lane >> 4;
    const int oc   = o0 + w * 16 + mr;

    f32x4 z = {0.f, 0.f, 0.f, 0.f};
    f32x4 acc[4] = {z, z, z, z};

    #pragma unroll
    for (int ksub = 0; ksub < 2; ++ksub) {
        const int rb = ksub * 4 + kg;
        bf16x8 bfA = *(const bf16x8*)&Ba[((size_t)rb * DOUT + oc) * 8];
        #pragma unroll
        for (int mt = 0; mt < 4; ++mt) {
            bf16x8 afB = *(const bf16x8*)&inter2[i2_idx(m0 / 16 + mt, rb, mr, 0)];
            acc[mt] = __builtin_amdgcn_mfma_f32_16x16x32_bf16(bfA, afB, acc[mt], 0, 0, 0);
        }
    }

    #pragma unroll
    for (int mt = 0; mt < 4; ++mt) {
        size_t off = (size_t)(m0 + mt * 16 + mr) * DOUT + o0 + w * 16 + kg * 4;
        float4 bv = *(const float4*)&base[off];
        float4 o;
        o.x = bv.x + s * acc[mt][0];
        o.y = bv.y + s * acc[mt][1];
        o.z = bv.z + s * acc[mt][2];
        o.w = bv.w + s * acc[mt][3];
        *(float4*)&out[off] = o;
    }
}

// ---------------------------------------------------------------------------
// Tier-2 k_xa (R11 register-pipeline, proven, ~117 us) for 10 MB ws.
// ---------------------------------------------------------------------------
__global__ __launch_bounds__(256, 1) void k_xa(
    const float* __restrict__ x, const int* __restrict__ idx,
    const __bf16* __restrict__ At2, __bf16* __restrict__ inter2)
{
    const int m0   = blockIdx.x * 64;
    const int a    = idx[m0 / TSEQ];
    const int w    = threadIdx.x >> 6, lane = threadIdx.x & 63;
    const int mr   = lane & 15, kg = lane >> 4;
    const float*  __restrict__ xrow = x + (size_t)(m0 + w * 16 + mr) * DIN + kg * 8;
    const __bf16* __restrict__ Aw = At2 + (size_t)a * RR * DIN + (size_t)(kg * 64 + mr) * 8;

    f32x4 z = {0.f, 0.f, 0.f, 0.f};
    f32x4 acc[4] = {z, z, z, z};
    float4 sx0[4], sx1[4];
    bf16x8 sa[4][4];

    #pragma unroll
    for (int s = 0; s < 4; ++s) {
        sx0[s] = *(const float4*)(xrow + s * 32);
        sx1[s] = *(const float4*)(xrow + s * 32 + 4);
        #pragma unroll
        for (int n = 0; n < 4; ++n)
            sa[s][n] = *(const bf16x8*)(Aw + ((size_t)s * 256 + n * 16) * 8);
    }

    #pragma unroll 4
    for (int ks = 0; ks < 124; ++ks) {
        const int s = ks & 3;
        float4 u0 = sx0[s], u1 = sx1[s];
        bf16x8 a0 = sa[s][0], a1 = sa[s][1], a2 = sa[s][2], a3 = sa[s][3];
        sx0[s] = *(const float4*)(xrow + (ks + 4) * 32);
        sx1[s] = *(const float4*)(xrow + (ks + 4) * 32 + 4);
        #pragma unroll
        for (int n = 0; n < 4; ++n)
            sa[s][n] = *(const bf16x8*)(Aw + ((size_t)(ks + 4) * 256 + n * 16) * 8);
        bf16x8 af = cvt8(u0, u1);
        acc[0] = __builtin_amdgcn_mfma_f32_16x16x32_bf16(af, a0, acc[0], 0, 0, 0);
        acc[1] = __builtin_amdgcn_mfma_f32_16x16x32_bf16(af, a1, acc[1], 0, 0, 0);
        acc[2] = __builtin_amdgcn_mfma_f32_16x16x32_bf16(af, a2, acc[2], 0, 0, 0);
        acc[3] = __builtin_amdgcn_mfma_f32_16x16x32_bf16(af, a3, acc[3], 0, 0, 0);
    }
    #pragma unroll
    for (int ks = 124; ks < 128; ++ks) {
        const int s = ks & 3;
        bf16x8 af = cvt8(sx0[s], sx1[s]);
        #pragma unroll
        for (int n = 0; n < 4; ++n)
            acc[n] = __builtin_amdgcn_mfma_f32_16x16x32_bf16(af, sa[s][n], acc[n], 0, 0, 0);
    }

    const int mblk = blockIdx.x * 4 + w;
    #pragma unroll
    for (int n = 0; n < 4; ++n) {
        const int rb = n * 2 + (mr >> 3), j = mr & 7;
        #pragma unroll
        for (int q = 0; q < 4; ++q)
            inter2[i2_idx(mblk, rb, kg * 4 + q, j)] = (__bf16)acc[n][q];
    }
}

// ---------------------------------------------------------------------------
// Fallback kernels (R6 verbatim, 2 MB ws).
// ---------------------------------------------------------------------------
__global__ __launch_bounds__(256) void k_xa_fb(
    const float* __restrict__ x, const int* __restrict__ idx,
    const float* __restrict__ A, __bf16* __restrict__ inter)
{
    const int m0   = blockIdx.x * 32;
    const int a    = idx[m0 / TSEQ];
    const float* __restrict__ Aa = A + (size_t)a * DIN * RR;
    const int lane = threadIdx.x & 63;
    const int rw   = threadIdx.x >> 6;
    const int mr   = lane & 15, kg = lane >> 4;
    const int rcol = rw * 16 + mr;
    const float* __restrict__ xrow0 = x + (size_t)(m0 + mr) * DIN;
    const float* __restrict__ xrow1 = x + (size_t)(m0 + 16 + mr) * DIN;

    f32x4 acc0 = {0.f, 0.f, 0.f, 0.f};
    f32x4 acc1 = {0.f, 0.f, 0.f, 0.f};

    for (int k0 = 0; k0 < DIN; k0 += 64) {
        #pragma unroll
        for (int ksub = 0; ksub < 2; ++ksub) {
            const int koff = k0 + ksub * 32 + kg * 8;
            float4 u0 = *(const float4*)&xrow0[koff];
            float4 u1 = *(const float4*)&xrow0[koff + 4];
            float4 v0 = *(const float4*)&xrow1[koff];
            float4 v1 = *(const float4*)&xrow1[koff + 4];
            bf16x8 af0 = cvt8(u0, u1);
            bf16x8 af1 = cvt8(v0, v1);
            const float* ap = &Aa[(size_t)koff * RR + rcol];
            bf16x8 bf;
            bf[0] = (__bf16)ap[0 * RR]; bf[1] = (__bf16)ap[1 * RR];
            bf[2] = (__bf16)ap[2 * RR]; bf[3] = (__bf16)ap[3 * RR];
            bf[4] = (__bf16)ap[4 * RR]; bf[5] = (__bf16)ap[5 * RR];
            bf[6] = (__bf16)ap[6 * RR]; bf[7] = (__bf16)ap[7 * RR];
            acc0 = __builtin_amdgcn_mfma_f32_16x16x32_bf16(af0, bf, acc0, 0, 0, 0);
            acc1 = __builtin_amdgcn_mfma_f32_16x16x32_bf16(af1, bf, acc1, 0, 0, 0);
        }
    }
    #pragma unroll
    for (int q = 0; q < 4; ++q) {
        inter[(size_t)(m0 + kg * 4 + q) * RR + rcol]      = (__bf16)acc0[q];
        inter[(size_t)(m0 + 16 + kg * 4 + q) * RR + rcol] = (__bf16)acc1[q];
    }
}

__global__ __launch_bounds__(256) void k_by_fb(
    const __bf16* __restrict__ inter, const float* __restrict__ base,
    const int* __restrict__ idx, const float* __restrict__ Bw,
    const float* __restrict__ scal, float* __restrict__ out)
{
    const int o0 = blockIdx.x * 64;
    const int m0 = blockIdx.y * 64;
    const int a  = idx[m0 / TSEQ];
    const float s = scal[a];
    const float* __restrict__ Ba = Bw + (size_t)a * RR * DOUT;
    const int lane = threadIdx.x & 63;
    const int w    = threadIdx.x >> 6;
    const int mr   = lane & 15, kg = lane >> 4;
    const int oc   = o0 + w * 16 + mr;

    f32x4 z = {0.f, 0.f, 0.f, 0.f};
    f32x4 acc[4] = {z, z, z, z};

    #pragma unroll
    for (int ksub = 0; ksub < 2; ++ksub) {
        const int kb = ksub * 32 + kg * 8;
        const float* bp = &Ba[(size_t)kb * DOUT + oc];
        bf16x8 bf;
        bf[0] = (__bf16)bp[0 * DOUT]; bf[1] = (__bf16)bp[1 * DOUT];
        bf[2] = (__bf16)bp[2 * DOUT]; bf[3] = (__bf16)bp[3 * DOUT];
        bf[4] = (__bf16)bp[4 * DOUT]; bf[5] = (__bf16)bp[5 * DOUT];
        bf[6] = (__bf16)bp[6 * DOUT]; bf[7] = (__bf16)bp[7 * DOUT];
        #pragma unroll
        for (int mt = 0; mt < 4; ++mt) {
            bf16x8 af = *(const bf16x8*)&inter[(size_t)(m0 + mt * 16 + mr) * RR + kb];
            acc[mt] = __builtin_amdgcn_mfma_f32_16x16x32_bf16(af, bf, acc[mt], 0, 0, 0);
        }
    }
    #pragma unroll
    for (int mt = 0; mt < 4; ++mt) {
        #pragma unroll
        for (int q = 0; q < 4; ++q) {
            size_t off = (size_t)(m0 + mt * 16 + kg * 4 + q) * DOUT + oc;
            out[off] = base[off] + s * acc[mt][q];
        }
    }
}

// ---------------------------------------------------------------------------
extern "C" void kernel_launch(void* const* d_in, const int* in_sizes, int n_in,
                              void* d_out, int out_size, void* d_ws, size_t ws_size,
                              hipStream_t stream)
{
    const float* x    = (const float*)d_in[0];
    const float* base = (const float*)d_in[1];
    const int*   idx  = (const int*)  d_in[2];
    const float* A    = (const float*)d_in[3];
    const float* Bw   = (const float*)d_in[4];
    const float* scal = (const float*)d_in[5];
    float* out = (float*)d_out;

    const size_t INTER_B = (size_t)BT * RR * 2;              // 2 MB
    const size_t AT_B    = (size_t)NADP * RR * DIN * 2;      // 4 MB
    const size_t BT_B    = (size_t)NADP * DOUT * RR * 2;     // 4 MB
    const size_t PART_B  = (size_t)NCH * INTER_B;            // 32 MB

    if (ws_size >= INTER_B + AT_B + BT_B + PART_B) {         // 42 MB: split-K
        __bf16* inter2 = (__bf16*)d_ws;
        __bf16* At2    = (__bf16*)((char*)d_ws + INTER_B);
        __bf16* Bp     = (__bf16*)((char*)d_ws + INTER_B + AT_B);
        __bf16* parts  = (__bf16*)((char*)d_ws + INTER_B + AT_B + BT_B);
        k_prep_a<<<dim3(1024), 256, 0, stream>>>(A, At2);
        k_prep_b<<<dim3(1024), 256, 0, stream>>>(Bw, Bp);
        k_xa_deep<<<dim3(BT / 256, NCH), 256, 0, stream>>>(x, idx, At2, parts);
        k_reduce<<<dim3(512),            256, 0, stream>>>(parts, inter2);
        k_by<<<dim3(DOUT / 64, BT / 64), 256, 0, stream>>>(inter2, base, idx, Bp, scal, out);
    } else if (ws_size >= INTER_B + AT_B + BT_B) {           // 10 MB: R11 path
        __bf16* inter2 = (__bf16*)d_ws;
        __bf16* At2    = (__bf16*)((char*)d_ws + INTER_B);
        __bf16* Bp     = (__bf16*)((char*)d_ws + INTER_B + AT_B);
        k_prep_a<<<dim3(1024), 256, 0, stream>>>(A, At2);
        k_prep_b<<<dim3(1024), 256, 0, stream>>>(Bw, Bp);
        k_xa<<<dim3(BT / 64),            256, 0, stream>>>(x, idx, At2, inter2);
        k_by<<<dim3(DOUT / 64, BT / 64), 256, 0, stream>>>(inter2, base, idx, Bp, scal, out);
    } else {                                                 // 2 MB fallback
        __bf16* inter = (__bf16*)d_ws;
        k_xa_fb<<<dim3(BT / 32),            256, 0, stream>>>(x, idx, A, inter);
        k_by_fb<<<dim3(DOUT / 64, BT / 64), 256, 0, stream>>>(inter, base, idx, Bw, scal, out);
    }
}

// Round 19
// 207.223 us; speedup vs baseline: 1.3256x; 1.0285x over previous
//
#include <hip/hip_runtime.h>
#include <hip/hip_bf16.h>
#include <cstdint>
#include <cstddef>

#define BT    16384   // B*T
#define DIN   4096
#define DOUT  4096
#define RR    64
#define TSEQ  2048
#define NADP  8

typedef float  f32x4  __attribute__((ext_vector_type(4)));
typedef __bf16 bf16x8 __attribute__((ext_vector_type(8)));

static __device__ __forceinline__ unsigned short bf16_bits(float f) {
    return __builtin_bit_cast(unsigned short, (__bf16)f);
}

// inter2 swizzled layout: [mblk(1024)][rb(8)][mrow(16)][j(8)]
static __device__ __forceinline__ size_t i2_idx(int mblk, int rb, int mrow, int j) {
    return ((((size_t)mblk * 8 + rb) * 16 + mrow) * 8 + j);
}

static __device__ __forceinline__ bf16x8 cvt8(float4 a, float4 b) {
    bf16x8 v;
    v[0] = (__bf16)a.x; v[1] = (__bf16)a.y; v[2] = (__bf16)a.z; v[3] = (__bf16)a.w;
    v[4] = (__bf16)b.x; v[5] = (__bf16)b.y; v[6] = (__bf16)b.z; v[7] = (__bf16)b.w;
    return v;
}

static __device__ __forceinline__ bf16x8 cvt8v(f32x4 a, f32x4 b) {
    bf16x8 v;
    v[0] = (__bf16)a[0]; v[1] = (__bf16)a[1]; v[2] = (__bf16)a[2]; v[3] = (__bf16)a[3];
    v[4] = (__bf16)b[0]; v[5] = (__bf16)b[1]; v[6] = (__bf16)b[2]; v[7] = (__bf16)b[3];
    return v;
}

// ---------------------------------------------------------------------------
// k_prep_a: At2[a][kq][r][j] = bf16(A[a][kq*8+j][r]).  (R8+ verbatim)
// ---------------------------------------------------------------------------
__global__ __launch_bounds__(256) void k_prep_a(
    const float* __restrict__ A, __bf16* __restrict__ At2)
{
    const int gtid = blockIdx.x * 256 + threadIdx.x;
    const int r  = gtid & 63;
    const int kb = (gtid >> 6) & (DIN / 8 - 1);
    const int a  = gtid >> 15;
    const float* __restrict__ src = A + (size_t)a * DIN * RR + (size_t)kb * 8 * RR + r;
    unsigned int u[4];
    #pragma unroll
    for (int p = 0; p < 4; ++p) {
        unsigned int lo = bf16_bits(src[(2 * p + 0) * RR]);
        unsigned int hi = bf16_bits(src[(2 * p + 1) * RR]);
        u[p] = lo | (hi << 16);
    }
    *(uint4*)&At2[(size_t)gtid * 8] = make_uint4(u[0], u[1], u[2], u[3]);
}

// ---------------------------------------------------------------------------
// k_prep_b: Bp[a][rb][o][j] = bf16(B[a][rb*8+j][o]).  (R8+ verbatim)
// ---------------------------------------------------------------------------
__global__ __launch_bounds__(256) void k_prep_b(
    const float* __restrict__ Bw, __bf16* __restrict__ Bp)
{
    const int gtid = blockIdx.x * 256 + threadIdx.x;
    const int o  = gtid & (DOUT - 1);
    const int rb = (gtid >> 12) & 7;
    const int a  = gtid >> 15;
    const float* __restrict__ src = Bw + (size_t)a * RR * DOUT + (size_t)rb * 8 * DOUT + o;
    unsigned int u[4];
    #pragma unroll
    for (int p = 0; p < 4; ++p) {
        unsigned int lo = bf16_bits(src[(2 * p + 0) * DOUT]);
        unsigned int hi = bf16_bits(src[(2 * p + 1) * DOUT]);
        u[p] = lo | (hi << 16);
    }
    *(uint4*)&Bp[(size_t)gtid * 8] = make_uint4(u[0], u[1], u[2], u[3]);
}

// ---------------------------------------------------------------------------
// k_xa: inter2 <- bf16( x @ A[a] ).  R13 structure, co-residency fix:
// 1024 blocks of 16 m-rows (4 blocks/CU via launch_bounds(256,4)), LDS
// [2][16][64] fp32 (8 KB dbuf). Stage = 1 float4 load + 1 ds_write per
// thread per tile (source slot pre-swizzled o^r, linear dest); read at
// physical slot l^mr (same involution, 2-way conflicts = free). Wave w:
// 16m x r-tile [w*16,+16), 2-barrier loop.  Store convention = R8-proven.
// ---------------------------------------------------------------------------
__global__ __launch_bounds__(256, 4) void k_xa(
    const float* __restrict__ x, const int* __restrict__ idx,
    const __bf16* __restrict__ At2, __bf16* __restrict__ inter2)
{
    __shared__ float xs[2][16][64];   // 8 KB double-buffered fp32 x-tile

    const int m0   = blockIdx.x * 16;
    const int a    = idx[m0 / TSEQ];
    const int w    = threadIdx.x >> 6, lane = threadIdx.x & 63;
    const int mr   = lane & 15, kg = lane >> 4;
    const int rcol = w * 16 + mr;

    const __bf16* __restrict__ Aw = At2 + (size_t)a * RR * DIN;

    // staging: thread -> (row sr, float4-slot so); source slot XOR-swizzled
    const int sr = threadIdx.x >> 4;          // 0..15
    const int so = threadIdx.x & 15;          // 0..15
    const float* __restrict__ gsrc = x + (size_t)(m0 + sr) * DIN + (so ^ sr) * 4;
    float* const d0 = &xs[0][sr][so * 4];
    float* const d1 = &xs[1][sr][so * 4];

    f32x4 acc = {0.f, 0.f, 0.f, 0.f};

#define STAGE(B, T)                                                     \
    {                                                                   \
        f32x4 sv = *(const f32x4*)(gsrc + (T) * 64);                    \
        *(f32x4*)((B) ? d1 : d0) = sv;                                  \
    }

#define COMPUTE(B, T)                                                             \
    {                                                                             \
        _Pragma("unroll")                                                         \
        for (int kstep = 0; kstep < 2; ++kstep) {                                 \
            const int kq = kstep * 4 + kg;                                        \
            bf16x8 bfw = *(const bf16x8*)&Aw[(((size_t)(T) * 8 + kq) * 64 + rcol) * 8]; \
            f32x4 lo = *(const f32x4*)&xs[B][mr][((2 * kq)     ^ mr) * 4];        \
            f32x4 hi = *(const f32x4*)&xs[B][mr][((2 * kq + 1) ^ mr) * 4];        \
            acc = __builtin_amdgcn_mfma_f32_16x16x32_bf16(cvt8v(lo, hi), bfw, acc, 0, 0, 0); \
        }                                                                         \
    }

    STAGE(0, 0)
    __syncthreads();

    for (int t = 0; t < 63; ++t) {
        STAGE((t + 1) & 1, t + 1)     // issue next tile while computing t
        COMPUTE(t & 1, t)
        __syncthreads();
    }
    COMPUTE(1, 63)

#undef STAGE
#undef COMPUTE

    // D layout (R8-proven): m = m0 + kg*4+q, r = rcol = w*16+mr
    const int rb = w * 2 + (mr >> 3), j = mr & 7;
    #pragma unroll
    for (int q = 0; q < 4; ++q)
        inter2[i2_idx(blockIdx.x, rb, kg * 4 + q, j)] = (__bf16)acc[q];
}

// ---------------------------------------------------------------------------
// k_by: out = base + s * (inter @ B).  (R8/R11/R13 verbatim, ~6.5 TB/s)
// ---------------------------------------------------------------------------
__global__ __launch_bounds__(256) void k_by(
    const __bf16* __restrict__ inter2, const float* __restrict__ base,
    const int* __restrict__ idx, const __bf16* __restrict__ Bp,
    const float* __restrict__ scal, float* __restrict__ out)
{
    const int o0 = blockIdx.x * 64;
    const int m0 = blockIdx.y * 64;
    const int a  = idx[m0 / TSEQ];
    const float s = scal[a];
    const __bf16* __restrict__ Ba = Bp + (size_t)a * RR * DOUT;
    const int lane = threadIdx.x & 63;
    const int w    = threadIdx.x >> 6;
    const int mr   = lane & 15, kg = lane >> 4;
    const int oc   = o0 + w * 16 + mr;

    f32x4 z = {0.f, 0.f, 0.f, 0.f};
    f32x4 acc[4] = {z, z, z, z};

    #pragma unroll
    for (int ksub = 0; ksub < 2; ++ksub) {
        const int rb = ksub * 4 + kg;
        bf16x8 bfA = *(const bf16x8*)&Ba[((size_t)rb * DOUT + oc) * 8];
        #pragma unroll
        for (int mt = 0; mt < 4; ++mt) {
            bf16x8 afB = *(const bf16x8*)&inter2[i2_idx(m0 / 16 + mt, rb, mr, 0)];
            acc[mt] = __builtin_amdgcn_mfma_f32_16x16x32_bf16(bfA, afB, acc[mt], 0, 0, 0);
        }
    }

    #pragma unroll
    for (int mt = 0; mt < 4; ++mt) {
        size_t off = (size_t)(m0 + mt * 16 + mr) * DOUT + o0 + w * 16 + kg * 4;
        float4 bv = *(const float4*)&base[off];
        float4 o;
        o.x = bv.x + s * acc[mt][0];
        o.y = bv.y + s * acc[mt][1];
        o.z = bv.z + s * acc[mt][2];
        o.w = bv.w + s * acc[mt][3];
        *(float4*)&out[off] = o;
    }
}

// ---------------------------------------------------------------------------
// Fallback kernels (R6 verbatim, 2 MB ws) if ws_size < 10 MB.
// ---------------------------------------------------------------------------
__global__ __launch_bounds__(256) void k_xa_fb(
    const float* __restrict__ x, const int* __restrict__ idx,
    const float* __restrict__ A, __bf16* __restrict__ inter)
{
    const int m0   = blockIdx.x * 32;
    const int a    = idx[m0 / TSEQ];
    const float* __restrict__ Aa = A + (size_t)a * DIN * RR;
    const int lane = threadIdx.x & 63;
    const int rw   = threadIdx.x >> 6;
    const int mr   = lane & 15, kg = lane >> 4;
    const int rcol = rw * 16 + mr;
    const float* __restrict__ xrow0 = x + (size_t)(m0 + mr) * DIN;
    const float* __restrict__ xrow1 = x + (size_t)(m0 + 16 + mr) * DIN;

    f32x4 acc0 = {0.f, 0.f, 0.f, 0.f};
    f32x4 acc1 = {0.f, 0.f, 0.f, 0.f};

    for (int k0 = 0; k0 < DIN; k0 += 64) {
        #pragma unroll
        for (int ksub = 0; ksub < 2; ++ksub) {
            const int koff = k0 + ksub * 32 + kg * 8;
            float4 u0 = *(const float4*)&xrow0[koff];
            float4 u1 = *(const float4*)&xrow0[koff + 4];
            float4 v0 = *(const float4*)&xrow1[koff];
            float4 v1 = *(const float4*)&xrow1[koff + 4];
            bf16x8 af0 = cvt8(u0, u1);
            bf16x8 af1 = cvt8(v0, v1);
            const float* ap = &Aa[(size_t)koff * RR + rcol];
            bf16x8 bf;
            bf[0] = (__bf16)ap[0 * RR]; bf[1] = (__bf16)ap[1 * RR];
            bf[2] = (__bf16)ap[2 * RR]; bf[3] = (__bf16)ap[3 * RR];
            bf[4] = (__bf16)ap[4 * RR]; bf[5] = (__bf16)ap[5 * RR];
            bf[6] = (__bf16)ap[6 * RR]; bf[7] = (__bf16)ap[7 * RR];
            acc0 = __builtin_amdgcn_mfma_f32_16x16x32_bf16(af0, bf, acc0, 0, 0, 0);
            acc1 = __builtin_amdgcn_mfma_f32_16x16x32_bf16(af1, bf, acc1, 0, 0, 0);
        }
    }
    #pragma unroll
    for (int q = 0; q < 4; ++q) {
        inter[(size_t)(m0 + kg * 4 + q) * RR + rcol]      = (__bf16)acc0[q];
        inter[(size_t)(m0 + 16 + kg * 4 + q) * RR + rcol] = (__bf16)acc1[q];
    }
}

__global__ __launch_bounds__(256) void k_by_fb(
    const __bf16* __restrict__ inter, const float* __restrict__ base,
    const int* __restrict__ idx, const float* __restrict__ Bw,
    const float* __restrict__ scal, float* __restrict__ out)
{
    const int o0 = blockIdx.x * 64;
    const int m0 = blockIdx.y * 64;
    const int a  = idx[m0 / TSEQ];
    const float s = scal[a];
    const float* __restrict__ Ba = Bw + (size_t)a * RR * DOUT;
    const int lane = threadIdx.x & 63;
    const int w    = threadIdx.x >> 6;
    const int mr   = lane & 15, kg = lane >> 4;
    const int oc   = o0 + w * 16 + mr;

    f32x4 z = {0.f, 0.f, 0.f, 0.f};
    f32x4 acc[4] = {z, z, z, z};

    #pragma unroll
    for (int ksub = 0; ksub < 2; ++ksub) {
        const int kb = ksub * 32 + kg * 8;
        const float* bp = &Ba[(size_t)kb * DOUT + oc];
        bf16x8 bf;
        bf[0] = (__bf16)bp[0 * DOUT]; bf[1] = (__bf16)bp[1 * DOUT];
        bf[2] = (__bf16)bp[2 * DOUT]; bf[3] = (__bf16)bp[3 * DOUT];
        bf[4] = (__bf16)bp[4 * DOUT]; bf[5] = (__bf16)bp[5 * DOUT];
        bf[6] = (__bf16)bp[6 * DOUT]; bf[7] = (__bf16)bp[7 * DOUT];
        #pragma unroll
        for (int mt = 0; mt < 4; ++mt) {
            bf16x8 af = *(const bf16x8*)&inter[(size_t)(m0 + mt * 16 + mr) * RR + kb];
            acc[mt] = __builtin_amdgcn_mfma_f32_16x16x32_bf16(af, bf, acc[mt], 0, 0, 0);
        }
    }
    #pragma unroll
    for (int mt = 0; mt < 4; ++mt) {
        #pragma unroll
        for (int q = 0; q < 4; ++q) {
            size_t off = (size_t)(m0 + mt * 16 + kg * 4 + q) * DOUT + oc;
            out[off] = base[off] + s * acc[mt][q];
        }
    }
}

// ---------------------------------------------------------------------------
extern "C" void kernel_launch(void* const* d_in, const int* in_sizes, int n_in,
                              void* d_out, int out_size, void* d_ws, size_t ws_size,
                              hipStream_t stream)
{
    const float* x    = (const float*)d_in[0];
    const float* base = (const float*)d_in[1];
    const int*   idx  = (const int*)  d_in[2];
    const float* A    = (const float*)d_in[3];
    const float* Bw   = (const float*)d_in[4];
    const float* scal = (const float*)d_in[5];
    float* out = (float*)d_out;

    const size_t INTER_B = (size_t)BT * RR * 2;              // 2 MB
    const size_t AT_B    = (size_t)NADP * RR * DIN * 2;      // 4 MB
    const size_t BT_B    = (size_t)NADP * DOUT * RR * 2;     // 4 MB

    if (ws_size >= INTER_B + AT_B + BT_B) {                  // 10 MB path
        __bf16* inter2 = (__bf16*)d_ws;
        __bf16* At2    = (__bf16*)((char*)d_ws + INTER_B);
        __bf16* Bp     = (__bf16*)((char*)d_ws + INTER_B + AT_B);
        k_prep_a<<<dim3(1024), 256, 0, stream>>>(A, At2);
        k_prep_b<<<dim3(1024), 256, 0, stream>>>(Bw, Bp);
        k_xa<<<dim3(BT / 16),            256, 0, stream>>>(x, idx, At2, inter2);
        k_by<<<dim3(DOUT / 64, BT / 64), 256, 0, stream>>>(inter2, base, idx, Bp, scal, out);
    } else {                                                 // 2 MB fallback
        __bf16* inter = (__bf16*)d_ws;
        k_xa_fb<<<dim3(BT / 32),            256, 0, stream>>>(x, idx, A, inter);
        k_by_fb<<<dim3(DOUT / 64, BT / 64), 256, 0, stream>>>(inter, base, idx, Bw, scal, out);
    }
}